// Round 9
// baseline (205.806 us; speedup 1.0000x reference)
//
#include <hip/hip_runtime.h>
#include <math.h>

// z:  (2,1,256,256,64)  idx = b*4194304 + x*16384 + y*64 + k
// tg: (2,3,256,256,64)  idx = b*12582912 + c*4194304 + x*16384 + y*64 + k
//
// wave = TWO cells (x,y0),(x,y0+1) (y0 even), lane = k. Round 8 proved the
// lane=k remap (VALU-bound, 0 bank conflicts, no spill); this round amortizes
// the redundant loads/shfls across a vertical cell pair:
//   - cell1's N row == cell2's C row, cell1's C row == cell2's S row
//   - cell2's b rows at y0+1 reuse cell1's loads AND their k+1 shfls
// loads 36->27, shfls 64->43 per 2 cells; math unchanged; peak live ~46
// floats (well under the 64-VGPR cliff seen in rounds 5/7).
// All per-cell expressions keep round-8's exact operand order; row k+1
// values are the shfl results themselves (never reconstructed).
// Block = 4 waves = 4x-adjacent column pairs. Grid = 2*64*128 = 16384.
//
// ws layout (floats), 32 slices x 258:
//   sl[p*258 + 0]=smooth, +1=div, +2+b*64+k = s1, +130+b*64+k = s2

__global__ __launch_bounds__(512) void zero_ws_kernel(float* ws) {
    for (int i = threadIdx.x; i < 32 * 258; i += 512) ws[i] = 0.0f;
}

__global__ __launch_bounds__(256, 4) void fused_loss_kernel(
    const float* __restrict__ zin, const float* __restrict__ tg,
    float* __restrict__ ws)
{
    __shared__ float r1[4][64];
    __shared__ float r2[4][64];
    __shared__ float rsc[4][2];

    const int tid  = threadIdx.x;
    const int lane = tid & 63;
    const int w    = tid >> 6;

    // blockIdx = bb*8192 + Y*64 + X ; wave w -> column x = 4X+w, rows y0=2Y, y0+1
    const int bb   = blockIdx.x >> 13;
    const int rest = blockIdx.x & 8191;
    const int X    = rest & 63;
    const int Y    = rest >> 6;
    const int x    = (X << 2) | w;
    const int y0   = Y << 1;               // 0..254, even

    const float* zb = zin + ((size_t)bb << 22);
    const int xp  = x < 255 ? x + 1 : 255;
    const int y2c = y0 < 254 ? y0 + 2 : 255;   // clamp only at y0==254 (uses masked)

    // ---- 6 z rows (center + east), one coalesced load each ----
    const float* zr  = zb + x  * 16384 + y0 * 64 + lane;
    const float* zrE = zb + xp * 16384 + y0 * 64 + lane;
    float z0  = zr[0];
    float z1  = zr[64];
    float z2  = zb[x  * 16384 + y2c * 64 + lane];
    float zE0 = zrE[0];
    float zE1 = zrE[64];
    float zE2 = zb[xp * 16384 + y2c * 64 + lane];

    float z0p  = __shfl_down(z0,  1, 64);   // lane63 garbage (masked k<63)
    float z1p  = __shfl_down(z1,  1, 64);
    float z2p  = __shfl_down(z2,  1, 64);
    float zE0p = __shfl_down(zE0, 1, 64);
    float zE1p = __shfl_down(zE1, 1, 64);
    float zE2p = __shfl_down(zE2, 1, 64);

    float dz0  = z0p  - z0;                 // dz rows, valid k<63
    float dz1  = z1p  - z1;
    float dz2  = z2p  - z2;
    float dzE0 = zE0p - zE0;
    float dzE1 = zE1p - zE1;
    float dzE2 = zE2p - zE2;

    // std partials: both cells, k<63
    float s1 = (lane < 63) ? (dz0 + dz1) : 0.0f;
    float s2 = (lane < 63) ? (dz0 * dz0 + dz1 * dz1) : 0.0f;

    // ---- smooth (wave-uniform guards; shfls outside lane guards) ----
    float sm = 0.0f;
    if (x >= 1 && x <= 254) {
        if (y0 >= 1) {                      // cell1: y=y0 (even => y0>=2)
            float zW0  = zb[(x - 1) * 16384 + y0 * 64 + lane];
            float zS   = zb[x * 16384 + (y0 - 1) * 64 + lane];
            float zW0p = __shfl_down(zW0, 1, 64);
            float zSp  = __shfl_down(zS,  1, 64);
            float dzW0 = zW0p - zW0;
            float dzS  = zSp  - zS;
            float dzm  = __shfl_up(dz0, 1, 64);
            float dzp  = __shfl_down(dz0, 1, 64);
            if (lane >= 1 && lane <= 61) {
                float lap = 6.0f * dz0 * dz0
                          - dzW0 * dzW0 - dzE0 * dzE0
                          - dzS * dzS   - dz1 * dz1
                          - dzm * dzm   - dzp * dzp;
                sm += lap * lap;
            }
        }
        if (y0 <= 253) {                    // cell2: y=y0+1 <= 254
            float zW1  = zb[(x - 1) * 16384 + (y0 + 1) * 64 + lane];
            float zW1p = __shfl_down(zW1, 1, 64);
            float dzW1 = zW1p - zW1;
            float dzm2 = __shfl_up(dz1, 1, 64);
            float dzp2 = __shfl_down(dz1, 1, 64);
            if (lane >= 1 && lane <= 61) {
                float lap = 6.0f * dz1 * dz1
                          - dzW1 * dzW1 - dzE1 * dzE1
                          - dz0 * dz0   - dz2 * dz2
                          - dzm2 * dzm2 - dzp2 * dzp2;
                sm += lap * lap;
            }
        }
    }

    // ---- div (cell1 always when x<255; cell2 when y0+1<255) ----
    float dv = 0.0f;
    if (x < 255) {
        const float* bB = tg + (((size_t)bb * 3) << 22) + x * 16384 + y0 * 64 + lane;
        const float* bY = bB + 4194304;
        const float* bZ = bB + 8388608;
        float bx0  = bB[0],   bxE0 = bB[16384];
        float bx1  = bB[64],  bxE1 = bB[16448];
        float by0  = bY[0],   byE0 = bY[16384];
        float by1  = bY[64],  byE1 = bY[16448];
        float bz0  = bZ[0],   bzE0 = bZ[16384];
        float bz1  = bZ[64],  bzE1 = bZ[16448];

        float bx0p  = __shfl_down(bx0,  1, 64);
        float bxE0p = __shfl_down(bxE0, 1, 64);
        float bx1p  = __shfl_down(bx1,  1, 64);
        float bxE1p = __shfl_down(bxE1, 1, 64);
        float by0p  = __shfl_down(by0,  1, 64);
        float byE0p = __shfl_down(byE0, 1, 64);
        float by1p  = __shfl_down(by1,  1, 64);
        float byE1p = __shfl_down(byE1, 1, 64);
        float bz0p  = __shfl_down(bz0,  1, 64);
        float bzE0p = __shfl_down(bzE0, 1, 64);
        float bz1p  = __shfl_down(bz1,  1, 64);
        float bzE1p = __shfl_down(bzE1, 1, 64);

        const float c6 = 1.0f / 6.0f;
        if (lane < 63) {
            // cell1: 00=(x,y0) 10=(x+1,y0) 01=(x,y0+1) 11=(x+1,y0+1)
            float adz00 = fabsf(dz0),  adz10 = fabsf(dzE0);
            float adz01 = fabsf(dz1),  adz11 = fabsf(dzE1);

            float num =
                0.125f * ( (bxE0 + bxE0p + bxE1 + bxE1p) * (adz10 + adz11)
                         - (bx0  + bx0p  + bx1  + bx1p ) * (adz00 + adz01)
                         + (by1  + by1p  + byE1 + byE1p) * (adz01 + adz11)
                         - (by0  + by0p  + byE0 + byE0p) * (adz00 + adz10) )
              + 0.25f * ( (bz0p + bzE0p + bz1p + bzE1p)
                        - (bz0  + bzE0  + bz1  + bzE1) );

            num += c6 * ( (bx0p  + bxE0p + bxE1p) * (z0p  - zE0p)
                        + (bx1p  + bxE1p + bxE0p) * (z1p  - zE1p)
                        + (byE0p + byE1p + by1p ) * (zE0p - zE1p)
                        + (by0p  + by1p  + byE1p) * (z0p  - z1p)
                        - (bx0  + bxE0 + bxE1) * (z0  - zE0)
                        - (bx1  + bxE1 + bxE0) * (z1  - zE1)
                        - (byE0 + byE1 + by1 ) * (zE0 - zE1)
                        - (by0  + by1  + byE1) * (z0  - z1) );

            float sbx = bx0 + bx0p + bxE0 + bxE0p + bx1 + bx1p + bxE1 + bxE1p;
            float sby = by0 + by0p + byE0 + byE0p + by1 + by1p + byE1 + byE1p;
            float sbz = bz0 + bz0p + bzE0 + bzE0p + bz1 + bz1p + bzE1 + bzE1p;
            float den = 0.015625f * (sbx * sbx + sby * sby + sbz * sbz) + 1e-10f;
            dv = num * num / den;
        }

        if (y0 + 1 < 255) {
            float bx2 = bB[128], bxE2 = bB[16512];
            float by2 = bY[128], byE2 = bY[16512];
            float bz2 = bZ[128], bzE2 = bZ[16512];
            float bx2p  = __shfl_down(bx2,  1, 64);
            float bxE2p = __shfl_down(bxE2, 1, 64);
            float by2p  = __shfl_down(by2,  1, 64);
            float byE2p = __shfl_down(byE2, 1, 64);
            float bz2p  = __shfl_down(bz2,  1, 64);
            float bzE2p = __shfl_down(bzE2, 1, 64);

            if (lane < 63) {
                // cell2: rows shift by one y (1->C, 2->N)
                float adz00 = fabsf(dz1),  adz10 = fabsf(dzE1);
                float adz01 = fabsf(dz2),  adz11 = fabsf(dzE2);

                float num =
                    0.125f * ( (bxE1 + bxE1p + bxE2 + bxE2p) * (adz10 + adz11)
                             - (bx1  + bx1p  + bx2  + bx2p ) * (adz00 + adz01)
                             + (by2  + by2p  + byE2 + byE2p) * (adz01 + adz11)
                             - (by1  + by1p  + byE1 + byE1p) * (adz00 + adz10) )
                  + 0.25f * ( (bz1p + bzE1p + bz2p + bzE2p)
                            - (bz1  + bzE1  + bz2  + bzE2) );

                num += c6 * ( (bx1p  + bxE1p + bxE2p) * (z1p  - zE1p)
                            + (bx2p  + bxE2p + bxE1p) * (z2p  - zE2p)
                            + (byE1p + byE2p + by2p ) * (zE1p - zE2p)
                            + (by1p  + by2p  + byE2p) * (z1p  - z2p)
                            - (bx1  + bxE1 + bxE2) * (z1  - zE1)
                            - (bx2  + bxE2 + bxE1) * (z2  - zE2)
                            - (byE1 + byE2 + by2 ) * (zE1 - zE2)
                            - (by1  + by2  + byE2) * (z1  - z2) );

                float sbx = bx1 + bx1p + bxE1 + bxE1p + bx2 + bx2p + bxE2 + bxE2p;
                float sby = by1 + by1p + byE1 + byE1p + by2 + by2p + byE2 + byE2p;
                float sbz = bz1 + bz1p + bzE1 + bzE1p + bz2 + bz2p + bzE2 + bzE2p;
                float den = 0.015625f * (sbx * sbx + sby * sby + sbz * sbz) + 1e-10f;
                dv += num * num / den;
            }
        }
    }

    // ---- reductions ----
    #pragma unroll
    for (int off = 32; off > 0; off >>= 1) {
        sm += __shfl_down(sm, off, 64);
        dv += __shfl_down(dv, off, 64);
    }
    r1[w][lane] = s1;
    r2[w][lane] = s2;
    if (lane == 0) { rsc[w][0] = sm; rsc[w][1] = dv; }
    __syncthreads();

    if (tid < 64) {
        float a   = r1[0][tid] + r1[1][tid] + r1[2][tid] + r1[3][tid];
        float b2r = r2[0][tid] + r2[1][tid] + r2[2][tid] + r2[3][tid];
        float* sl = ws + (blockIdx.x & 31) * 258;
        if (tid < 63) {
            atomicAdd(&sl[2 + bb * 64 + tid],   a);
            atomicAdd(&sl[130 + bb * 64 + tid], b2r);
        }
        if (tid == 0) atomicAdd(&sl[0], rsc[0][0] + rsc[1][0] + rsc[2][0] + rsc[3][0]);
        if (tid == 1) atomicAdd(&sl[1], rsc[0][1] + rsc[1][1] + rsc[2][1] + rsc[3][1]);
    }
}

__global__ __launch_bounds__(128) void finalize_kernel(const float* __restrict__ ws,
                                                       float* __restrict__ out)
{
    __shared__ double red[128];
    const int t = threadIdx.x;
    double stdv = 0.0;
    {
        int k = t & 63, bb = t >> 6;
        if (k < 63) {
            double s1 = 0.0, s2 = 0.0;
            for (int p = 0; p < 32; ++p) {
                s1 += (double)ws[p * 258 + 2 + bb * 64 + k];
                s2 += (double)ws[p * 258 + 130 + bb * 64 + k];
            }
            const double N = 65536.0;
            double var = (s2 - s1 * s1 / N) / (N - 1.0);
            stdv = sqrt(var > 0.0 ? var : 0.0);
        }
    }
    red[t] = stdv;
    __syncthreads();
    for (int off = 64; off > 0; off >>= 1) {
        if (t < off) red[t] += red[t + off];
        __syncthreads();
    }
    if (t == 0) {
        double smt = 0.0, dvt = 0.0;
        for (int p = 0; p < 32; ++p) {
            smt += (double)ws[p * 258 + 0];
            dvt += (double)ws[p * 258 + 1];
        }
        double loss_std    = red[0] / 126.0;
        double loss_smooth = smt / (2.0 * 254.0 * 254.0 * 61.0);
        double loss_div    = dvt / (2.0 * 255.0 * 255.0 * 63.0);
        out[0] = (float)(loss_div * 1e9);
        out[1] = (float)(loss_smooth * 10.0 + loss_std * 100.0);
    }
}

extern "C" void kernel_launch(void* const* d_in, const int* in_sizes, int n_in,
                              void* d_out, int out_size, void* d_ws, size_t ws_size,
                              hipStream_t stream) {
    const float* z  = (const float*)d_in[0];   // outputs (2,1,256,256,64)
    const float* tg = (const float*)d_in[1];   // targets (2,3,256,256,64)
    float* out = (float*)d_out;
    float* ws  = (float*)d_ws;

    zero_ws_kernel<<<1, 512, 0, stream>>>(ws);
    // 2 batches x (64 X-tiles x 128 Y-tiles) = 16384 blocks, 4 waves each
    fused_loss_kernel<<<16384, 256, 0, stream>>>(z, tg, ws);
    finalize_kernel<<<1, 128, 0, stream>>>(ws, out);
}

// Round 10
// 181.869 us; speedup vs baseline: 1.1316x; 1.1316x over previous
//
#include <hip/hip_runtime.h>
#include <math.h>

// z:  (2,1,256,256,64)  idx = b*4194304 + x*16384 + y*64 + k
// tg: (2,3,256,256,64)  idx = b*12582912 + c*4194304 + x*16384 + y*64 + k
//
// wave = one (x,y) cell, lane = k (round-8 structure: 0 bank conflicts, no
// spill, 74% occupancy). Round-10 changes:
//  1. ALL 18 row loads hoisted to the top with clamped addresses -> memory
//     latency overlaps the z-shfl/smooth phase (R8 exposed the b-load
//     latency after smooth). Boundary clamps are masked by the same guards
//     as before (loads are always in-bounds, values unused where invalid).
//  2. b k+1 neighbors shuffled as PRE-SUMMED combos (9 shfls instead of 12)
//     since every p-value is only consumed inside one of 9 fixed sums;
//     also deletes ~15 adds. (Sum reassociation already proven tolerant:
//     earlier rounds reassociated these sums freely with absmax 0.)
// Block = 4 waves = 2x2 cells. Grid = 2 x 128x128 = 32768.
//
// ws layout (floats), 32 slices x 258:
//   sl[p*258 + 0]=smooth, +1=div, +2+b*64+k = s1, +130+b*64+k = s2

__global__ __launch_bounds__(512) void zero_ws_kernel(float* ws) {
    for (int i = threadIdx.x; i < 32 * 258; i += 512) ws[i] = 0.0f;
}

__global__ __launch_bounds__(256, 4) void fused_loss_kernel(
    const float* __restrict__ zin, const float* __restrict__ tg,
    float* __restrict__ ws)
{
    __shared__ float r1[4][64];
    __shared__ float r2[4][64];
    __shared__ float rsc[4][2];

    const int tid  = threadIdx.x;
    const int lane = tid & 63;
    const int w    = tid >> 6;

    // blockIdx = bb*16384 + ty*128 + tx ; wave w -> cell (2tx + (w>>1), 2ty + (w&1))
    const int bb   = blockIdx.x >> 14;
    const int rest = blockIdx.x & 16383;
    const int tx   = rest & 127;
    const int ty   = rest >> 7;
    const int x    = (tx << 1) | (w >> 1);
    const int y    = (ty << 1) | (w & 1);

    const int xp = x < 255 ? x + 1 : 255;
    const int yp = y < 255 ? y + 1 : 255;
    const int xm = x > 0 ? x - 1 : 0;
    const int ym = y > 0 ? y - 1 : 0;

    const int o00 = x  * 16384 + y  * 64 + lane;
    const int o10 = xp * 16384 + y  * 64 + lane;
    const int o01 = x  * 16384 + yp * 64 + lane;
    const int o11 = xp * 16384 + yp * 64 + lane;

    // ---- all row loads issued up front (latency overlaps shfl/smooth) ----
    const float* zb = zin + ((size_t)bb << 22);
    float zC  = zb[o00];
    float zE  = zb[o10];
    float zN  = zb[o01];
    float zNE = zb[o11];
    float zW  = zb[xm * 16384 + y * 64 + lane];
    float zS  = zb[x * 16384 + ym * 64 + lane];

    const float* tbx = tg + (((size_t)bb * 3) << 22);
    const float* tby = tbx + 4194304;
    const float* tbz = tbx + 8388608;
    float bx00 = tbx[o00], bx10 = tbx[o10], bx01 = tbx[o01], bx11 = tbx[o11];
    float by00 = tby[o00], by10 = tby[o10], by01 = tby[o01], by11 = tby[o11];
    float bz00 = tbz[o00], bz10 = tbz[o10], bz01 = tbz[o01], bz11 = tbz[o11];

    // ---- z k+1 neighbors + dz rows ----
    float zCp  = __shfl_down(zC,  1, 64);   // lane63 garbage (masked k<63)
    float zEp  = __shfl_down(zE,  1, 64);
    float zNp  = __shfl_down(zN,  1, 64);
    float zNEp = __shfl_down(zNE, 1, 64);
    float zWp  = __shfl_down(zW,  1, 64);
    float zSp  = __shfl_down(zS,  1, 64);

    float dz   = zCp  - zC;
    float dzE  = zEp  - zE;
    float dzN  = zNp  - zN;
    float dzNE = zNEp - zNE;
    float dzW  = zWp  - zW;
    float dzS  = zSp  - zS;

    float dzm = __shfl_up(dz, 1, 64);       // dz[k-1]; lane0 garbage (masked)
    float dzp = __shfl_down(dz, 1, 64);     // dz[k+1]

    // std partials (k<63 valid) -- covers ALL x,y
    float s1 = (lane < 63) ? dz : 0.0f;
    float s2 = (lane < 63) ? dz * dz : 0.0f;

    // ---- smooth (value-masked; loads/shfls already done) ----
    float sm = 0.0f;
    if (x >= 1 && x <= 254 && y >= 1 && y <= 254 && lane >= 1 && lane <= 61) {
        float lap = 6.0f * dz * dz
                  - dzW * dzW - dzE * dzE
                  - dzS * dzS - dzN * dzN
                  - dzm * dzm - dzp * dzp;
        sm = lap * lap;
    }

    // ---- div (uniform xy guard; pre-summed b shfls: 9 instead of 12) ----
    float dv = 0.0f;
    if (x < 255 && y < 255) {
        float bxA = bx00 + bx01;            // W face pair
        float bxB = bx10 + bx11;            // E face pair
        float bxC = bxB + bx00;             // bx00+bx10+bx11
        float bxD = bxB + bx01;             // bx01+bx11+bx10
        float byQ = by00 + by10;            // S face pair
        float byP = by01 + by11;            // N face pair
        float byR = byP + by10;             // by10+by11+by01
        float byS = byP + by00;             // by00+by01+by11
        float bzT = ((bz00 + bz10) + bz01) + bz11;

        float bxAp = __shfl_down(bxA, 1, 64);
        float bxBp = __shfl_down(bxB, 1, 64);
        float bxCp = __shfl_down(bxC, 1, 64);
        float bxDp = __shfl_down(bxD, 1, 64);
        float byQp = __shfl_down(byQ, 1, 64);
        float byPp = __shfl_down(byP, 1, 64);
        float byRp = __shfl_down(byR, 1, 64);
        float bySp = __shfl_down(byS, 1, 64);
        float bzTp = __shfl_down(bzT, 1, 64);

        if (lane < 63) {
            float adz00 = fabsf(dz),  adz10 = fabsf(dzE);
            float adz01 = fabsf(dzN), adz11 = fabsf(dzNE);

            float num =
                0.125f * ( (bxB + bxBp) * (adz10 + adz11)
                         - (bxA + bxAp) * (adz00 + adz01)
                         + (byP + byPp) * (adz01 + adz11)
                         - (byQ + byQp) * (adz00 + adz10) )
              + 0.25f * ( bzTp - bzT );

            const float c6 = 1.0f / 6.0f;
            num += c6 * ( bxCp * (zCp - zEp)
                        + bxDp * (zNp - zNEp)
                        + byRp * (zEp - zNEp)
                        + bySp * (zCp - zNp)
                        - bxC * (zC - zE)
                        - bxD * (zN - zNE)
                        - byR * (zE - zNE)
                        - byS * (zC - zN) );

            float sbx = (bxA + bxB) + (bxAp + bxBp);
            float sby = (byQ + byP) + (byQp + byPp);
            float sbz = bzT + bzTp;
            float den = 0.015625f * (sbx * sbx + sby * sby + sbz * sbz) + 1e-10f;
            dv = num * num / den;
        }
    }

    // ---- reductions ----
    #pragma unroll
    for (int off = 32; off > 0; off >>= 1) {
        sm += __shfl_down(sm, off, 64);
        dv += __shfl_down(dv, off, 64);
    }
    r1[w][lane] = s1;
    r2[w][lane] = s2;
    if (lane == 0) { rsc[w][0] = sm; rsc[w][1] = dv; }
    __syncthreads();

    if (tid < 64) {
        float a   = r1[0][tid] + r1[1][tid] + r1[2][tid] + r1[3][tid];
        float b2r = r2[0][tid] + r2[1][tid] + r2[2][tid] + r2[3][tid];
        float* sl = ws + (blockIdx.x & 31) * 258;
        if (tid < 63) {
            atomicAdd(&sl[2 + bb * 64 + tid],   a);
            atomicAdd(&sl[130 + bb * 64 + tid], b2r);
        }
        if (tid == 0) atomicAdd(&sl[0], rsc[0][0] + rsc[1][0] + rsc[2][0] + rsc[3][0]);
        if (tid == 1) atomicAdd(&sl[1], rsc[0][1] + rsc[1][1] + rsc[2][1] + rsc[3][1]);
    }
}

__global__ __launch_bounds__(128) void finalize_kernel(const float* __restrict__ ws,
                                                       float* __restrict__ out)
{
    __shared__ double red[128];
    const int t = threadIdx.x;
    double stdv = 0.0;
    {
        int k = t & 63, bb = t >> 6;
        if (k < 63) {
            double s1 = 0.0, s2 = 0.0;
            for (int p = 0; p < 32; ++p) {
                s1 += (double)ws[p * 258 + 2 + bb * 64 + k];
                s2 += (double)ws[p * 258 + 130 + bb * 64 + k];
            }
            const double N = 65536.0;
            double var = (s2 - s1 * s1 / N) / (N - 1.0);
            stdv = sqrt(var > 0.0 ? var : 0.0);
        }
    }
    red[t] = stdv;
    __syncthreads();
    for (int off = 64; off > 0; off >>= 1) {
        if (t < off) red[t] += red[t + off];
        __syncthreads();
    }
    if (t == 0) {
        double smt = 0.0, dvt = 0.0;
        for (int p = 0; p < 32; ++p) {
            smt += (double)ws[p * 258 + 0];
            dvt += (double)ws[p * 258 + 1];
        }
        double loss_std    = red[0] / 126.0;
        double loss_smooth = smt / (2.0 * 254.0 * 254.0 * 61.0);
        double loss_div    = dvt / (2.0 * 255.0 * 255.0 * 63.0);
        out[0] = (float)(loss_div * 1e9);
        out[1] = (float)(loss_smooth * 10.0 + loss_std * 100.0);
    }
}

extern "C" void kernel_launch(void* const* d_in, const int* in_sizes, int n_in,
                              void* d_out, int out_size, void* d_ws, size_t ws_size,
                              hipStream_t stream) {
    const float* z  = (const float*)d_in[0];   // outputs (2,1,256,256,64)
    const float* tg = (const float*)d_in[1];   // targets (2,3,256,256,64)
    float* out = (float*)d_out;
    float* ws  = (float*)d_ws;

    zero_ws_kernel<<<1, 512, 0, stream>>>(ws);
    // 2 batches x 128x128 tiles of 2x2 cells = 32768 blocks
    fused_loss_kernel<<<32768, 256, 0, stream>>>(z, tg, ws);
    finalize_kernel<<<1, 128, 0, stream>>>(ws, out);
}